// Round 3
// baseline (152.849 us; speedup 1.0000x reference)
//
#include <hip/hip_runtime.h>
#include <math.h>

#define ALPHA 32.0f
#define MRG 0.1f
#define STAT_WEIGHT 0.01f
#define STAT_ADJ_W 0.15f
#define COS_EPS 1e-8f

typedef __attribute__((ext_vector_type(8))) short bf16x8;
typedef __attribute__((ext_vector_type(4))) float f32x4;
typedef __attribute__((ext_vector_type(4))) unsigned int u32x4;

__device__ __forceinline__ ushort f2bf(float f) {
    unsigned u = __float_as_uint(f);
    return (ushort)((u + 0x7FFFu + ((u >> 16) & 1u)) >> 16);   // RNE
}
__device__ __forceinline__ unsigned pk2(float a, float b) {
    return (unsigned)f2bf(a) | ((unsigned)f2bf(b) << 16);
}

// block-wide (128 threads = 2 waves) sum reduce, result broadcast to all
__device__ __forceinline__ float bred128(float v, float* sm, int d) {
    #pragma unroll
    for (int off = 1; off < 64; off <<= 1) v += __shfl_xor(v, off);
    if ((d & 63) == 0) sm[d >> 6] = v;
    __syncthreads();
    float r = sm[0] + sm[1];
    __syncthreads();
    return r;
}

// ---------------- K1: per-sample stats; writes SWIZZLED Xn16 row, adj, n_valid -
// Parallel membership scan (4 LDS reads/thread) replaces the old 512-iteration
// serial chain; owner block (min member index) computes the class stats in
// ascending-j order (bit-identical to the original serial version).
// Swizzle: 16-byte group g of row b stored at group g ^ (b & 15), matching
// k_main's fragment ds_reads (bank-spread after a plain contiguous copy).
__global__ void k_stats(const float* __restrict__ X, const float* __restrict__ proxies,
                        const float* __restrict__ cc, const int* __restrict__ T,
                        ushort* __restrict__ Xn16, float* __restrict__ adj,
                        float* __restrict__ scal, int B) {
    const int b = blockIdx.x, d = threadIdx.x;   // d in [0,128) == dim index
    __shared__ int Tl[512];
    __shared__ float sm[2];
    __shared__ int mlist[512];
    __shared__ int mcnt;
    for (int i = d; i < B; i += 128) Tl[i] = T[i];
    if (d == 0) mcnt = 0;
    __syncthreads();
    const int c = Tl[b];

    // own row: normalize + swizzled bf16 store
    float x = X[(size_t)b * 128 + d];
    float n2 = bred128(x * x, sm, d);
    float xn = x * rsqrtf(n2 + 1e-12f);
    const int pk = ((((d >> 3) ^ (b & 15)) << 3) | (d & 7));   // swizzled column
    Xn16[(size_t)b * 128 + pk] = f2bf(xn);

    // parallel membership scan
    for (int j = d; j < B; j += 128)
        if (Tl[j] == c) mlist[atomicAdd(&mcnt, 1)] = j;
    __syncthreads();
    const int cnt = mcnt;
    int minj = mlist[0];
    for (int i = 1; i < cnt; ++i) minj = min(minj, mlist[i]);
    if (minj != b) return;                       // earlier block owns this class

    // member stats in ascending-j order (deterministic)
    float sd = 0.f, qd = 0.f;
    int prev = -1;
    for (int rank = 0; rank < cnt; ++rank) {
        int cur = 0x7fffffff;
        for (int i = 0; i < cnt; ++i) { int v = mlist[i]; if (v > prev && v < cur) cur = v; }
        prev = cur;
        float xj = X[(size_t)cur * 128 + d];
        float nj = bred128(xj * xj, sm, d);
        float xnj = xj * rsqrtf(nj + 1e-12f);
        sd += xnj; qd += xnj * xnj;
    }
    float fc = (float)cnt;
    float m = sd / fc;
    float var = fminf(fmaxf(qd / fc - m * m, 1e-6f), 10.0f);
    float sv = bred128(var, sm, d);

    float p  = proxies[(size_t)c * 128 + d];
    float cv = cc[(size_t)c * 128 + d];
    float s2 = bred128(p * p, sm, d);
    float c2 = bred128(cv * cv, sm, d);
    float pc = bred128(p * cv, sm, d);
    if (d == 0) {
        float inv = rsqrtf(s2 + 1e-12f);
        float pn = fmaxf(sqrtf(s2) * inv, COS_EPS);
        float cn = fmaxf(sqrtf(c2), COS_EPS);
        float censim = (pc * inv) / (pn * cn);
        float vw = 1.0f / (1.0f + sv * (1.0f / 128.0f));
        adj[c] = censim * vw * STAT_ADJ_W;
        atomicAdd(&scal[3], 1.0f);
    }
}

// ---------------- K2: LDS-staged A (double-buffered), register B ---------------
// 782 blocks x 64 classes, 256 threads. ONE 16-class tile per wave (was 2):
// doubles resident waves to ~12/CU (3/SIMD) so the stage-barrier/ds_read/MFMA
// latency chains overlap across ~3 blocks/CU. Staging pipeline is byte-for-byte
// the proven round-0 shape (8 chunks x 64 rows, double-buffered, one barrier
// per chunk, source-swizzled fragment reads). Per-class accumulation order is
// bit-identical to the 2-tile version (chunk -> rt -> r -> quad shuffle).
__launch_bounds__(256, 2)
__global__ void k_main(const float* __restrict__ proxies, const float* __restrict__ cc,
                       const ushort* __restrict__ Xsw, const int* __restrict__ T,
                       const float* __restrict__ adj, float* __restrict__ scal,
                       float* __restrict__ out, int C, int nblk) {
    const int tid = threadIdx.x, lane = tid & 63, wv = tid >> 6;
    const int nlo = lane & 15, quad = lane >> 4;
    const int c0 = blockIdx.x * 64;

    __shared__ ushort Sx[16384];      // 2 x 16 KB double buffer
    __shared__ int Tl[512];
    __shared__ float red[4][3];
    Tl[tid] = T[tid];
    Tl[tid + 256] = T[tid + 256];

    // ---- cc |.| partial for this block's 64-class slice ----
    float cabs = 0.f;
    {
        const int n4 = ((c0 + 64 <= C) ? 64 : (C - c0)) * 32;
        const float4* cp = (const float4*)(cc + (size_t)c0 * 128);
        #pragma unroll 4
        for (int i = tid; i < n4; i += 256) {
            float4 v = cp[i];
            cabs += fabsf(v.x) + fabsf(v.y) + fabsf(v.z) + fabsf(v.w);
        }
    }

    // ---- B fragment: ONE 16-class tile per wave, normalized in-register ----
    const int cls0 = c0 + wv * 16 + nlo;
    bf16x8 bfr[4];
    {
        int cl = (cls0 < C) ? cls0 : C - 1;
        const float4* pr = (const float4*)(proxies + (size_t)cl * 128);
        float4 v0[4], v1[4];
        float s2 = 0.f;
        #pragma unroll
        for (int ks = 0; ks < 4; ++ks) {
            v0[ks] = pr[ks * 8 + quad * 2];
            v1[ks] = pr[ks * 8 + quad * 2 + 1];
            s2 += v0[ks].x*v0[ks].x + v0[ks].y*v0[ks].y + v0[ks].z*v0[ks].z + v0[ks].w*v0[ks].w
                + v1[ks].x*v1[ks].x + v1[ks].y*v1[ks].y + v1[ks].z*v1[ks].z + v1[ks].w*v1[ks].w;
        }
        s2 += __shfl_xor(s2, 16);
        s2 += __shfl_xor(s2, 32);
        float pin = rsqrtf(s2 + 1e-12f);
        #pragma unroll
        for (int ks = 0; ks < 4; ++ks) {
            u32x4 u;
            u.x = pk2(v0[ks].x * pin, v0[ks].y * pin);
            u.y = pk2(v0[ks].z * pin, v0[ks].w * pin);
            u.z = pk2(v1[ks].x * pin, v1[ks].y * pin);
            u.w = pk2(v1[ks].z * pin, v1[ks].w * pin);
            bfr[ks] = __builtin_bit_cast(bf16x8, u);
        }
    }

    // ---- fragment LDS offsets (in ushorts); swizzle index is nlo ----
    int fro[4];
    #pragma unroll
    for (int ks = 0; ks < 4; ++ks)
        fro[ks] = nlo * 128 + (((ks * 4 + quad) ^ nlo) << 3);

    // ---- staging pipeline: chunk = 64 rows = 16 KB = 1024 uint4 ----
    const uint4* gX = (const uint4*)Xsw;
    uint4 s0, s1, s2v, s3;
    #define LOADV(ch) { const uint4* p_ = gX + (ch) * 1024 + tid; \
                        s0 = p_[0]; s1 = p_[256]; s2v = p_[512]; s3 = p_[768]; }
    #define WRITEV(bi) { uint4* q_ = (uint4*)&Sx[(bi) * 8192]; \
                         q_[tid] = s0; q_[tid + 256] = s1; q_[tid + 512] = s2v; q_[tid + 768] = s3; }
    LOADV(0); WRITEV(0); LOADV(1);
    __syncthreads();

    float pp0 = 0.f, np0 = 0.f;
    for (int chunk = 0; chunk < 8; ++chunk) {
        const int bo = (chunk & 1) * 8192;
        if (chunk < 7) {
            WRITEV((chunk + 1) & 1);          // stage next (regs loaded last epoch)
            if (chunk < 6) LOADV(chunk + 2);  // issue loads for chunk+2 now
        }
        #pragma unroll
        for (int rt = 0; rt < 4; ++rt) {
            const ushort* sb = &Sx[bo + rt * 2048];
            bf16x8 a0 = *(const bf16x8*)&sb[fro[0]];
            bf16x8 a1 = *(const bf16x8*)&sb[fro[1]];
            bf16x8 a2 = *(const bf16x8*)&sb[fro[2]];
            bf16x8 a3 = *(const bf16x8*)&sb[fro[3]];
            f32x4 acc0 = {0.f,0.f,0.f,0.f};
            acc0 = __builtin_amdgcn_mfma_f32_16x16x32_bf16(a0, bfr[0], acc0, 0, 0, 0);
            acc0 = __builtin_amdgcn_mfma_f32_16x16x32_bf16(a1, bfr[1], acc0, 0, 0, 0);
            acc0 = __builtin_amdgcn_mfma_f32_16x16x32_bf16(a2, bfr[2], acc0, 0, 0, 0);
            acc0 = __builtin_amdgcn_mfma_f32_16x16x32_bf16(a3, bfr[3], acc0, 0, 0, 0);

            int4 t4 = *(const int4*)&Tl[chunk * 64 + rt * 16 + quad * 4];
            int tvs[4] = {t4.x, t4.y, t4.z, t4.w};
            #pragma unroll
            for (int r = 0; r < 4; ++r) {
                bool po = (tvs[r] == cls0); float v = acc0[r];
                float e = __expf(po ? -ALPHA * (v - MRG) : ALPHA * (v + MRG));
                pp0 += po ? e : 0.f; np0 += po ? 0.f : e;
            }
        }
        __syncthreads();
    }
    #undef LOADV
    #undef WRITEV

    // ---- per-class totals across quads; adj factor; log1p (wave owns classes) --
    pp0 += __shfl_xor(pp0, 16); pp0 += __shfl_xor(pp0, 32);
    np0 += __shfl_xor(np0, 16); np0 += __shfl_xor(np0, 32);

    float lp = 0.f, ln = 0.f;
    {
        float a0 = adj[(cls0 < C) ? cls0 : C - 1];
        float as0 = (pp0 > 0.f) ? a0 : 0.f;     // absent class => adj = 0
        if (cls0 < C) {
            lp += log1pf(pp0 * __expf(-ALPHA * as0));
            ln += log1pf(np0 * __expf( ALPHA * as0));
        }
    }
    // quads hold identical values; sum across nlo
    #pragma unroll
    for (int off = 1; off < 16; off <<= 1) {
        lp += __shfl_xor(lp, off);
        ln += __shfl_xor(ln, off);
    }
    #pragma unroll
    for (int off = 1; off < 64; off <<= 1) cabs += __shfl_xor(cabs, off);

    if (lane == 0) { red[wv][0] = lp; red[wv][1] = ln; red[wv][2] = cabs; }
    __syncthreads();
    if (tid == 0) {
        atomicAdd(&scal[0], red[0][0] + red[1][0] + red[2][0] + red[3][0]);
        atomicAdd(&scal[1], red[0][1] + red[1][1] + red[2][1] + red[3][1]);
        atomicAdd(&scal[2], red[0][2] + red[1][2] + red[2][2] + red[3][2]);
        __threadfence();
        unsigned old = atomicAdd((unsigned*)(scal + 4), 1u);
        if (old == (unsigned)(nblk - 1)) {
            float S0 = atomicAdd(&scal[0], 0.f);
            float S1 = atomicAdd(&scal[1], 0.f);
            float S2 = atomicAdd(&scal[2], 0.f);
            float S3 = atomicAdd(&scal[3], 0.f);
            out[0] = S0 / S3 + S1 / (float)C + STAT_WEIGHT * (S2 / ((float)C * 128.f));
        }
    }
}

extern "C" void kernel_launch(void* const* d_in, const int* in_sizes, int n_in,
                              void* d_out, int out_size, void* d_ws, size_t ws_size,
                              hipStream_t stream) {
    const float* X       = (const float*)d_in[0];
    const int*   T       = (const int*)d_in[1];
    const float* proxies = (const float*)d_in[2];
    const float* cc      = (const float*)d_in[3];
    float* out = (float*)d_out;

    const int B = in_sizes[1];            // 512
    const int D = in_sizes[0] / B;        // 128
    const int C = in_sizes[2] / D;        // 50000

    float*  adj  = (float*)d_ws;                       // C (only present classes touched)
    float*  scal = adj + C;                            // 8 (zeroed)
    ushort* Xn16 = (ushort*)(scal + 8);                // B*D bf16, swizzled layout

    const int nblk = (C + 63) / 64;                    // 782

    (void)hipMemsetAsync(scal, 0, 8 * sizeof(float), stream);
    k_stats<<<B, 128, 0, stream>>>(X, proxies, cc, T, Xn16, adj, scal, B);
    k_main<<<nblk, 256, 0, stream>>>(proxies, cc, Xn16, T, adj, scal, out, C, nblk);
}

// Round 4
// 135.658 us; speedup vs baseline: 1.1267x; 1.1267x over previous
//
#include <hip/hip_runtime.h>
#include <math.h>

#define ALPHA 32.0f
#define MRG 0.1f
#define STAT_WEIGHT 0.01f
#define STAT_ADJ_W 0.15f
#define COS_EPS 1e-8f

typedef __attribute__((ext_vector_type(8))) short bf16x8;
typedef __attribute__((ext_vector_type(4))) float f32x4;
typedef __attribute__((ext_vector_type(4))) unsigned int u32x4;

__device__ __forceinline__ ushort f2bf(float f) {
    unsigned u = __float_as_uint(f);
    return (ushort)((u + 0x7FFFu + ((u >> 16) & 1u)) >> 16);   // RNE
}
__device__ __forceinline__ unsigned pk2(float a, float b) {
    return (unsigned)f2bf(a) | ((unsigned)f2bf(b) << 16);
}

// block-wide (128 threads = 2 waves) sum reduce, result broadcast to all
__device__ __forceinline__ float bred128(float v, float* sm, int d) {
    #pragma unroll
    for (int off = 1; off < 64; off <<= 1) v += __shfl_xor(v, off);
    if ((d & 63) == 0) sm[d >> 6] = v;
    __syncthreads();
    float r = sm[0] + sm[1];
    __syncthreads();
    return r;
}

// ---------------- K1: per-sample stats; writes SWIZZLED Xn16 row, adj, n_valid -
// Parallel membership scan; owner block (min member index) computes class stats
// in ascending-j order. Swizzle: 16-byte group g of row b stored at g ^ (b&15).
__global__ void k_stats(const float* __restrict__ X, const float* __restrict__ proxies,
                        const float* __restrict__ cc, const int* __restrict__ T,
                        ushort* __restrict__ Xn16, float* __restrict__ adj,
                        float* __restrict__ scal, int B) {
    const int b = blockIdx.x, d = threadIdx.x;   // d in [0,128) == dim index
    __shared__ int Tl[512];
    __shared__ float sm[2];
    __shared__ int mlist[512];
    __shared__ int mcnt;
    for (int i = d; i < B; i += 128) Tl[i] = T[i];
    if (d == 0) mcnt = 0;
    __syncthreads();
    const int c = Tl[b];

    // own row: normalize + swizzled bf16 store
    float x = X[(size_t)b * 128 + d];
    float n2 = bred128(x * x, sm, d);
    float xn = x * rsqrtf(n2 + 1e-12f);
    const int pk = ((((d >> 3) ^ (b & 15)) << 3) | (d & 7));   // swizzled column
    Xn16[(size_t)b * 128 + pk] = f2bf(xn);

    // parallel membership scan
    for (int j = d; j < B; j += 128)
        if (Tl[j] == c) mlist[atomicAdd(&mcnt, 1)] = j;
    __syncthreads();
    const int cnt = mcnt;
    int minj = mlist[0];
    for (int i = 1; i < cnt; ++i) minj = min(minj, mlist[i]);
    if (minj != b) return;                       // earlier block owns this class

    // member stats in ascending-j order (deterministic)
    float sd = 0.f, qd = 0.f;
    int prev = -1;
    for (int rank = 0; rank < cnt; ++rank) {
        int cur = 0x7fffffff;
        for (int i = 0; i < cnt; ++i) { int v = mlist[i]; if (v > prev && v < cur) cur = v; }
        prev = cur;
        float xj = X[(size_t)cur * 128 + d];
        float nj = bred128(xj * xj, sm, d);
        float xnj = xj * rsqrtf(nj + 1e-12f);
        sd += xnj; qd += xnj * xnj;
    }
    float fc = (float)cnt;
    float m = sd / fc;
    float var = fminf(fmaxf(qd / fc - m * m, 1e-6f), 10.0f);
    float sv = bred128(var, sm, d);

    float p  = proxies[(size_t)c * 128 + d];
    float cv = cc[(size_t)c * 128 + d];
    float s2 = bred128(p * p, sm, d);
    float c2 = bred128(cv * cv, sm, d);
    float pc = bred128(p * cv, sm, d);
    if (d == 0) {
        float inv = rsqrtf(s2 + 1e-12f);
        float pn = fmaxf(sqrtf(s2) * inv, COS_EPS);
        float cn = fmaxf(sqrtf(c2), COS_EPS);
        float censim = (pc * inv) / (pn * cn);
        float vw = 1.0f / (1.0f + sv * (1.0f / 128.0f));
        adj[c] = censim * vw * STAT_ADJ_W;
        atomicAdd(&scal[3], 1.0f);
    }
}

// ---------------- K2: LDS-staged A, ROW-SPLIT grid (391 x 2) -------------------
// Round-2 proven shape (128 classes/block, 2 class-tiles/wave) but each block
// stages only its 256-row HALF: 4 chunks, 4 barriers. Total staging across the
// device is unchanged (round-3 lesson: total stage work is the dominant term);
// residency doubles to ~3 blocks/CU so barrier drains overlap. Per-class pp/np
// become 2-block partials -> atomicAdd into Psum/Nsum (exactly 2 contributors
// per address: deterministic FP). log1p/adj moved to k_fin where totals live.
__launch_bounds__(256, 2)
__global__ void k_main(const float* __restrict__ proxies, const float* __restrict__ cc,
                       const ushort* __restrict__ Xsw, const int* __restrict__ T,
                       float* __restrict__ Psum, float* __restrict__ Nsum,
                       float* __restrict__ scal, int C) {
    const int tid = threadIdx.x, lane = tid & 63, wv = tid >> 6;
    const int nlo = lane & 15, quad = lane >> 4;
    const int c0 = blockIdx.x * 128;
    const int half = blockIdx.y;                  // 0/1: which 256-row half
    const int r0 = half * 256;

    __shared__ ushort Sx[16384];      // 2 x 16 KB double buffer
    __shared__ alignas(16) int Tl[256];
    __shared__ float red[4];
    Tl[tid] = T[r0 + tid];

    // ---- cc |.| partial for this block's 128-class slice (half 0 only) ----
    float cabs = 0.f;
    if (half == 0) {
        const int n4 = ((c0 + 128 <= C) ? 128 : (C - c0)) * 32;
        const float4* cp = (const float4*)(cc + (size_t)c0 * 128);
        #pragma unroll 4
        for (int i = tid; i < n4; i += 256) {
            float4 v = cp[i];
            cabs += fabsf(v.x) + fabsf(v.y) + fabsf(v.z) + fabsf(v.w);
        }
    }

    // ---- B fragments: 2 class-tiles, normalized in-register (proven shape) ----
    const int cls0 = c0 + wv * 32 + nlo;
    const int cls1 = cls0 + 16;
    bf16x8 bfr[2][4];
    #pragma unroll
    for (int t = 0; t < 2; ++t) {
        int cls = c0 + wv * 32 + t * 16 + nlo;
        int cl = (cls < C) ? cls : C - 1;
        const float4* pr = (const float4*)(proxies + (size_t)cl * 128);
        float4 v0[4], v1[4];
        float s2 = 0.f;
        #pragma unroll
        for (int ks = 0; ks < 4; ++ks) {
            v0[ks] = pr[ks * 8 + quad * 2];
            v1[ks] = pr[ks * 8 + quad * 2 + 1];
            s2 += v0[ks].x*v0[ks].x + v0[ks].y*v0[ks].y + v0[ks].z*v0[ks].z + v0[ks].w*v0[ks].w
                + v1[ks].x*v1[ks].x + v1[ks].y*v1[ks].y + v1[ks].z*v1[ks].z + v1[ks].w*v1[ks].w;
        }
        s2 += __shfl_xor(s2, 16);
        s2 += __shfl_xor(s2, 32);
        float pin = rsqrtf(s2 + 1e-12f);
        #pragma unroll
        for (int ks = 0; ks < 4; ++ks) {
            u32x4 u;
            u.x = pk2(v0[ks].x * pin, v0[ks].y * pin);
            u.y = pk2(v0[ks].z * pin, v0[ks].w * pin);
            u.z = pk2(v1[ks].x * pin, v1[ks].y * pin);
            u.w = pk2(v1[ks].z * pin, v1[ks].w * pin);
            bfr[t][ks] = __builtin_bit_cast(bf16x8, u);
        }
    }

    // ---- fragment LDS offsets (in ushorts); swizzle index is nlo ----
    // global row = half*256 + chunk*64 + rt*16 + nlo; low 4 bits == nlo, so the
    // k_stats swizzle (b & 15) is matched unchanged.
    int fro[4];
    #pragma unroll
    for (int ks = 0; ks < 4; ++ks)
        fro[ks] = nlo * 128 + (((ks * 4 + quad) ^ nlo) << 3);

    // ---- staging pipeline: 4 chunks x 64 rows = 16 KB = 1024 uint4 each ----
    const uint4* gX = (const uint4*)Xsw + half * 4096;
    uint4 s0, s1, s2v, s3;
    #define LOADV(ch) { const uint4* p_ = gX + (ch) * 1024 + tid; \
                        s0 = p_[0]; s1 = p_[256]; s2v = p_[512]; s3 = p_[768]; }
    #define WRITEV(bi) { uint4* q_ = (uint4*)&Sx[(bi) * 8192]; \
                         q_[tid] = s0; q_[tid + 256] = s1; q_[tid + 512] = s2v; q_[tid + 768] = s3; }
    LOADV(0); WRITEV(0); LOADV(1);
    __syncthreads();

    float pp0 = 0.f, np0 = 0.f, pp1 = 0.f, np1 = 0.f;
    for (int chunk = 0; chunk < 4; ++chunk) {
        const int bo = (chunk & 1) * 8192;
        if (chunk < 3) {
            WRITEV((chunk + 1) & 1);          // stage next (regs loaded last epoch)
            if (chunk < 2) LOADV(chunk + 2);  // issue loads for chunk+2 now
        }
        #pragma unroll
        for (int rt = 0; rt < 4; ++rt) {
            const ushort* sb = &Sx[bo + rt * 2048];
            bf16x8 a0 = *(const bf16x8*)&sb[fro[0]];
            bf16x8 a1 = *(const bf16x8*)&sb[fro[1]];
            bf16x8 a2 = *(const bf16x8*)&sb[fro[2]];
            bf16x8 a3 = *(const bf16x8*)&sb[fro[3]];
            f32x4 acc0 = {0.f,0.f,0.f,0.f}, acc1 = {0.f,0.f,0.f,0.f};
            acc0 = __builtin_amdgcn_mfma_f32_16x16x32_bf16(a0, bfr[0][0], acc0, 0, 0, 0);
            acc1 = __builtin_amdgcn_mfma_f32_16x16x32_bf16(a0, bfr[1][0], acc1, 0, 0, 0);
            acc0 = __builtin_amdgcn_mfma_f32_16x16x32_bf16(a1, bfr[0][1], acc0, 0, 0, 0);
            acc1 = __builtin_amdgcn_mfma_f32_16x16x32_bf16(a1, bfr[1][1], acc1, 0, 0, 0);
            acc0 = __builtin_amdgcn_mfma_f32_16x16x32_bf16(a2, bfr[0][2], acc0, 0, 0, 0);
            acc1 = __builtin_amdgcn_mfma_f32_16x16x32_bf16(a2, bfr[1][2], acc1, 0, 0, 0);
            acc0 = __builtin_amdgcn_mfma_f32_16x16x32_bf16(a3, bfr[0][3], acc0, 0, 0, 0);
            acc1 = __builtin_amdgcn_mfma_f32_16x16x32_bf16(a3, bfr[1][3], acc1, 0, 0, 0);

            int4 t4 = *(const int4*)&Tl[chunk * 64 + rt * 16 + quad * 4];
            int tvs[4] = {t4.x, t4.y, t4.z, t4.w};
            #pragma unroll
            for (int r = 0; r < 4; ++r) {
                { bool po = (tvs[r] == cls0); float v = acc0[r];
                  float e = __expf(po ? -ALPHA * (v - MRG) : ALPHA * (v + MRG));
                  pp0 += po ? e : 0.f; np0 += po ? 0.f : e; }
                { bool po = (tvs[r] == cls1); float v = acc1[r];
                  float e = __expf(po ? -ALPHA * (v - MRG) : ALPHA * (v + MRG));
                  pp1 += po ? e : 0.f; np1 += po ? 0.f : e; }
            }
        }
        __syncthreads();
    }
    #undef LOADV
    #undef WRITEV

    // ---- per-class half-totals across quads -> global atomics ----
    pp0 += __shfl_xor(pp0, 16); pp0 += __shfl_xor(pp0, 32);
    np0 += __shfl_xor(np0, 16); np0 += __shfl_xor(np0, 32);
    pp1 += __shfl_xor(pp1, 16); pp1 += __shfl_xor(pp1, 32);
    np1 += __shfl_xor(np1, 16); np1 += __shfl_xor(np1, 32);
    if (quad == 0) {
        if (cls0 < C) { atomicAdd(&Psum[cls0], pp0); atomicAdd(&Nsum[cls0], np0); }
        if (cls1 < C) { atomicAdd(&Psum[cls1], pp1); atomicAdd(&Nsum[cls1], np1); }
    }

    // ---- cabs block reduce (half 0 only) ----
    if (half == 0) {
        #pragma unroll
        for (int off = 1; off < 64; off <<= 1) cabs += __shfl_xor(cabs, off);
        if (lane == 0) red[wv] = cabs;
        __syncthreads();
        if (tid == 0) atomicAdd(&scal[2], red[0] + red[1] + red[2] + red[3]);
    }
}

// ---------------- K3: per-class log1p + final reduce ---------------------------
__launch_bounds__(256)
__global__ void k_fin(const float* __restrict__ Psum, const float* __restrict__ Nsum,
                      const float* __restrict__ adj, float* __restrict__ scal,
                      float* __restrict__ out, int C, int nfin) {
    const int tid = threadIdx.x, lane = tid & 63, wv = tid >> 6;
    const int c = blockIdx.x * 256 + tid;
    __shared__ float red[4][2];
    float lp = 0.f, ln = 0.f;
    if (c < C) {
        float p = Psum[c], n = Nsum[c];
        float a = (p > 0.f) ? adj[c] : 0.f;      // has_samples <=> p > 0
        lp = log1pf(p * __expf(-ALPHA * a));
        ln = log1pf(n * __expf( ALPHA * a));
    }
    #pragma unroll
    for (int off = 1; off < 64; off <<= 1) {
        lp += __shfl_xor(lp, off);
        ln += __shfl_xor(ln, off);
    }
    if (lane == 0) { red[wv][0] = lp; red[wv][1] = ln; }
    __syncthreads();
    if (tid == 0) {
        atomicAdd(&scal[0], red[0][0] + red[1][0] + red[2][0] + red[3][0]);
        atomicAdd(&scal[1], red[0][1] + red[1][1] + red[2][1] + red[3][1]);
        __threadfence();
        unsigned old = atomicAdd((unsigned*)(scal + 4), 1u);
        if (old == (unsigned)(nfin - 1)) {
            float S0 = atomicAdd(&scal[0], 0.f);
            float S1 = atomicAdd(&scal[1], 0.f);
            float S2 = atomicAdd(&scal[2], 0.f);
            float S3 = atomicAdd(&scal[3], 0.f);
            out[0] = S0 / S3 + S1 / (float)C + STAT_WEIGHT * (S2 / ((float)C * 128.f));
        }
    }
}

extern "C" void kernel_launch(void* const* d_in, const int* in_sizes, int n_in,
                              void* d_out, int out_size, void* d_ws, size_t ws_size,
                              hipStream_t stream) {
    const float* X       = (const float*)d_in[0];
    const int*   T       = (const int*)d_in[1];
    const float* proxies = (const float*)d_in[2];
    const float* cc      = (const float*)d_in[3];
    float* out = (float*)d_out;

    const int B = in_sizes[1];            // 512
    const int D = in_sizes[0] / B;        // 128
    const int C = in_sizes[2] / D;        // 50000

    // workspace layout: [Psum C][Nsum C][scal 8][adj C][Xn16 B*D bf16]
    float*  Psum = (float*)d_ws;
    float*  Nsum = Psum + C;
    float*  scal = Nsum + C;                           // 8
    float*  adj  = scal + 8;                           // C (only present classes touched)
    ushort* Xn16 = (ushort*)(adj + C);                 // B*D bf16, swizzled layout

    const int nblk = (C + 127) / 128;                  // 391
    const int nfin = (C + 255) / 256;                  // 196

    (void)hipMemsetAsync(Psum, 0, (2 * (size_t)C + 8) * sizeof(float), stream);
    k_stats<<<B, 128, 0, stream>>>(X, proxies, cc, T, Xn16, adj, scal, B);
    k_main<<<dim3(nblk, 2), 256, 0, stream>>>(proxies, cc, Xn16, T, Psum, Nsum, scal, C);
    k_fin<<<nfin, 256, 0, stream>>>(Psum, Nsum, adj, scal, out, C, nfin);
}